// Round 3
// baseline (339.681 us; speedup 1.0000x reference)
//
#include <hip/hip_runtime.h>

// PartPP: per (frame, part, channel) segment mean+max pooling.
// x: (32, 256, 30, 16, 16) fp32 ; labels: (32, 30, 16, 16) int ; out: (32, 256, 30, 16) fp32
//
// R3: split metadata out. Kernel 1 (960 blocks) computes per-frame bucket-sort
// metadata ONCE (rank[256], offs[17] per frame -> d_ws, ~1.1 MB, L2-resident).
// Kernel 2 (7680 blocks) is then a pure streaming kernel with a SINGLE barrier:
//   global float4 loads + rank int4 load issue at wave start -> LDS bucket-scatter
//   -> barrier -> contiguous per-part reduce -> float2 store.
// No atomics, no scan, no metadata barriers in the hot kernel.

#define C_DIM 256
#define S_DIM 30
#define P_NUM 16
#define HW 256
#define CH_PER_BLK 32
#define TS 260   // floats per LDS row: 16B-aligned rows; stride%32==4 decorrelates banks

// ---------------- kernel 1: per-frame metadata ----------------
__global__ __launch_bounds__(256)
void partpp_meta_kernel(const int* __restrict__ labels,
                        int* __restrict__ rank_g,     // (960, 256)
                        int* __restrict__ offs_g) {   // (960, 32) first 17 used
    __shared__ int counts[P_NUM], cursor[P_NUM], offs[P_NUM + 1];
    const int t = threadIdx.x;
    const int f = blockIdx.x;

    if (t < P_NUM) { counts[t] = 0; cursor[t] = 0; }
    __syncthreads();
    const int lab = labels[f * HW + t];
    atomicAdd(&counts[lab], 1);
    __syncthreads();
    if (t == 0) {
        int acc = 0;
        #pragma unroll
        for (int p = 0; p < P_NUM; ++p) { offs[p] = acc; acc += counts[p]; }
        offs[P_NUM] = acc;  // == 256
    }
    __syncthreads();
    rank_g[f * HW + t] = offs[lab] + atomicAdd(&cursor[lab], 1);
    if (t < P_NUM + 1) offs_g[f * 32 + t] = offs[t];
}

// ---------------- kernel 2: streaming pool ----------------
__global__ __launch_bounds__(256, 4)
void partpp_pool_kernel(const float* __restrict__ x,
                        const int* __restrict__ rank_g,
                        const int* __restrict__ offs_g,
                        float* __restrict__ out) {
    __shared__ float tile[CH_PER_BLK * TS];   // 33280 B
    __shared__ int offs_sh[P_NUM + 1];

    const int t   = threadIdx.x;
    const int b   = blockIdx.x;
    const int f   = b >> 3;                 // frame 0..959 (f = n*30 + s)
    const int q   = b & 7;                  // channel octant
    const int ch0 = q * CH_PER_BLK;
    const int n   = f / S_DIM;
    const int s   = f - n * S_DIM;
    const int col = t & 63;                 // float4 column 0..63
    const int w   = t >> 6;                 // wave id 0..3

    // ---- issue all global loads immediately ----
    const int4 rk = ((const int4*)(rank_g + f * HW))[col];   // L2-hot, broadcast across waves

    const size_t xbase = ((size_t)(n * C_DIM + ch0) * S_DIM + s) * HW;
    float4 v[8];
    #pragma unroll
    for (int j = 0; j < 8; ++j) {
        const int row = j * 4 + w;          // per wave: contiguous 1KB row segments
        v[j] = *(const float4*)(x + xbase + (size_t)row * (S_DIM * HW) + col * 4);
    }
    if (t < P_NUM + 1) offs_sh[t] = offs_g[f * 32 + t];

    // ---- scatter into bucket-sorted LDS layout ----
    #pragma unroll
    for (int j = 0; j < 8; ++j) {
        const int row = j * 4 + w;
        float* rp = &tile[row * TS];
        rp[rk.x] = v[j].x;
        rp[rk.y] = v[j].y;
        rp[rk.z] = v[j].z;
        rp[rk.w] = v[j].w;
    }
    __syncthreads();   // the ONLY barrier

    // ---- reduce: thread = (channel, part-pair); contiguous LDS reads ----
    const int ch  = t >> 3;    // 0..31
    const int sub = t & 7;     // parts {2*sub, 2*sub+1}
    const float* rowp = &tile[ch * TS];

    float res[2];
    #pragma unroll
    for (int pi = 0; pi < 2; ++pi) {
        const int p  = sub * 2 + pi;
        const int jb = offs_sh[p];
        const int je = offs_sh[p + 1];
        float sum = 0.0f;
        float mx  = -3.0e38f;
        for (int j = jb; j < je; ++j) {
            const float vv = rowp[j];       // independent reads -> pipelined
            sum += vv;
            mx = fmaxf(mx, vv);
        }
        // torch scatter_reduce amax include_self(-100); empty part -> 0
        res[pi] = (je > jb) ? (sum / (float)(je - jb) + fmaxf(mx, -100.0f)) : 0.0f;
    }

    // out[((n*C + c)*S + s)*P + p]; 8 lanes -> 64B contiguous per channel
    float* op = out + ((size_t)(n * C_DIM + ch0 + ch) * S_DIM + s) * P_NUM + sub * 2;
    *(float2*)op = make_float2(res[0], res[1]);
}

extern "C" void kernel_launch(void* const* d_in, const int* in_sizes, int n_in,
                              void* d_out, int out_size, void* d_ws, size_t ws_size,
                              hipStream_t stream) {
    const float* x      = (const float*)d_in[0];
    const int*   labels = (const int*)d_in[1];
    float*       out    = (float*)d_out;

    int* rank_g = (int*)d_ws;                 // 960*256 ints
    int* offs_g = rank_g + 960 * HW;          // 960*32 ints

    hipLaunchKernelGGL(partpp_meta_kernel, dim3(960), dim3(256), 0, stream,
                       labels, rank_g, offs_g);
    hipLaunchKernelGGL(partpp_pool_kernel, dim3(960 * 8), dim3(256), 0, stream,
                       x, rank_g, offs_g, out);
}